// Round 3
// baseline (331.710 us; speedup 1.0000x reference)
//
#include <hip/hip_runtime.h>

// NeuromodulatedAttention — MI355X (gfx950), round 3
//
// ALGEBRA: (1) the dopamine/serotonin "mod" is a per-row constant added before
// per-row mean/std normalization -> cancels exactly (MLPs are dead code).
// (2) the mean subtraction is a per-row constant inside softmax -> also cancels.
// Effective computation:  out = softmax( S * istd_row ) @ V,
//   S = Q K^T / sqrt(512),  istd_row = 1/(std(S_row, ddof=1) + 1e-6).
//
// Round-3 deltas vs round 2 (which was per-wave load-LATENCY bound: MfmaUtil
// 9.8%, VALUBusy 10.2%, 80% idle):
//   * explicit register prefetch (rotating cur/nxt groups of 4 k-steps, fully
//     unrolled) in pass-1 QK, pass-2 QK and pass-2 PV -> ~16 global 16B loads
//     in flight per wave instead of ~8, hiding ~400cyc L2 latency.
//   * pass 1 reshaped to 2 accumulators x 4 k-tiles (VGPR headroom for the
//     prefetch buffers; stats identical).
//   * transpose_v rewritten: 64x64 tiles, float4 loads, 16B coalesced stores
//     (was ~60us with scalar 2B stores).

#define BB 4
#define SS 2048
#define DD 512
#define SCALE 0.044194173824159216f  // 1/sqrt(512)
#define LOG2E 1.4426950408889634f

typedef __bf16 bf16;
typedef bf16 bf16x2 __attribute__((ext_vector_type(2)));
typedef bf16 bf16x4 __attribute__((ext_vector_type(4)));
typedef bf16 bf16x8 __attribute__((ext_vector_type(8)));
typedef float f32x16 __attribute__((ext_vector_type(16)));

// ---------------- precast kernels ----------------

__global__ void cast_qk_kernel(const float* __restrict__ Q, const float* __restrict__ K,
                               bf16* __restrict__ Qb, bf16* __restrict__ Kb) {
  size_t i = ((size_t)blockIdx.x * 256 + threadIdx.x) * 8;
  float4 a0 = *(const float4*)(Q + i);
  float4 a1 = *(const float4*)(Q + i + 4);
  bf16x8 qa = { (bf16)a0.x, (bf16)a0.y, (bf16)a0.z, (bf16)a0.w,
                (bf16)a1.x, (bf16)a1.y, (bf16)a1.z, (bf16)a1.w };
  *(bf16x8*)(Qb + i) = qa;
  float4 b0 = *(const float4*)(K + i);
  float4 b1 = *(const float4*)(K + i + 4);
  bf16x8 ka = { (bf16)b0.x, (bf16)b0.y, (bf16)b0.z, (bf16)b0.w,
                (bf16)b1.x, (bf16)b1.y, (bf16)b1.z, (bf16)b1.w };
  *(bf16x8*)(Kb + i) = ka;
}

// V [b][s][d] fp32 -> Vt [b][d][s] bf16. 64x64 tiles, 256 threads.
__global__ void transpose_v_kernel(const float* __restrict__ V, bf16* __restrict__ Vt) {
  __shared__ bf16 tile[64][80];   // [d][s], padded row = 160B (16B-aligned)
  const int b = blockIdx.z;
  const int s0 = blockIdx.x * 64, d0 = blockIdx.y * 64;
  const int t = threadIdx.x;
  const int r16 = t >> 4;         // 0..15  (s-row within tile)
  const int c4  = (t & 15) * 4;   // 0..60  (d-col within tile)
#pragma unroll
  for (int i = 0; i < 4; ++i) {
    int r = i * 16 + r16;
    float4 v = *(const float4*)&V[((size_t)b * SS + s0 + r) * DD + d0 + c4];
    tile[c4 + 0][r] = (bf16)v.x;
    tile[c4 + 1][r] = (bf16)v.y;
    tile[c4 + 2][r] = (bf16)v.z;
    tile[c4 + 3][r] = (bf16)v.w;
  }
  __syncthreads();
  const int dr8 = t >> 3;         // 0..31
  const int sc8 = (t & 7) * 8;    // 0..56
#pragma unroll
  for (int i = 0; i < 2; ++i) {
    int dr = i * 32 + dr8;
    bf16x8 o = *(const bf16x8*)&tile[dr][sc8];
    *(bf16x8*)&Vt[((size_t)b * DD + d0 + dr) * SS + s0 + sc8] = o;
  }
}

// ---------------- main attention kernel (fast path) ----------------

// XOR-swizzled element index inside a 32x512 bf16 LDS tile.
__device__ __forceinline__ int sw(int row, int col) {
  return row * 512 + ((((col >> 3) ^ (row & 7))) << 3) + (col & 7);
}

__launch_bounds__(512, 2)
__global__ void nm_attn3_kernel(const bf16* __restrict__ Qw,
                                const bf16* __restrict__ Kw,
                                const bf16* __restrict__ Vw,
                                float* __restrict__ Op) {
  __shared__ bf16 Qs[32 * 512];   // 32 KB, swizzled
  __shared__ bf16 Ps[32 * 512];   // 32 KB, swizzled; stats scratch overlaid
  float* scratch = (float*)Ps;

  const int tid  = threadIdx.x;
  const int w    = tid >> 6;          // wave 0..7
  const int lane = tid & 63;
  const int l31  = lane & 31;
  const int lh8  = (lane >> 5) * 8;
  const int bid  = blockIdx.x;
  // XCD swizzle: consecutive blocks round-robin XCDs; pin batch b to XCDs {2b,2b+1}
  const int b  = (bid & 7) >> 1;
  const int qt = ((bid >> 3) << 1) | (bid & 1);
  const int q0 = qt * 32;

  // ---- stage Q tile (32 x 512 bf16) into swizzled LDS ----
  {
    const bf16* Qb = Qw + ((size_t)b * SS + q0) * DD;
#pragma unroll
    for (int i = 0; i < 4; ++i) {
      int f = i * 512 + tid;
      int row = f >> 6, g = f & 63;
      bf16x8 v = *(const bf16x8*)&Qb[(size_t)row * DD + g * 8];
      *(bf16x8*)&Qs[row * 512 + ((g ^ (row & 7)) << 3)] = v;
    }
  }
  __syncthreads();

  int qrow[16];
#pragma unroll
  for (int r = 0; r < 16; ++r) qrow[r] = (r & 3) + 8 * (r >> 2) + 4 * (lane >> 5);

  // ================= PASS 1: row sum / sumsq of scaled scores =================
  // Wave w owns k-cols [kt*512 + w*64, +64) per kt; 4 kt cover all 2048 k.
  float sumv[16], sqv[16];
#pragma unroll
  for (int r = 0; r < 16; ++r) { sumv[r] = 0.f; sqv[r] = 0.f; }

  for (int kt = 0; kt < 4; ++kt) {
    const bf16* Kb = Kw + ((size_t)b * SS + kt * 512 + w * 64) * DD;
    f32x16 c0 = {}, c1 = {};
    // register prefetch pipeline: groups of 4 k-steps, cur/nxt rotation
    bf16x8 cur[4][2], nxt[4][2];
#pragma unroll
    for (int j = 0; j < 4; ++j) {
      cur[j][0] = *(const bf16x8*)&Kb[(size_t)(l31)      * DD + j * 16 + lh8];
      cur[j][1] = *(const bf16x8*)&Kb[(size_t)(32 + l31) * DD + j * 16 + lh8];
    }
#pragma unroll
    for (int g = 0; g < 8; ++g) {
      if (g < 7) {
#pragma unroll
        for (int j = 0; j < 4; ++j) {
          int kk = (g + 1) * 4 + j;
          nxt[j][0] = *(const bf16x8*)&Kb[(size_t)(l31)      * DD + kk * 16 + lh8];
          nxt[j][1] = *(const bf16x8*)&Kb[(size_t)(32 + l31) * DD + kk * 16 + lh8];
        }
      }
#pragma unroll
      for (int j = 0; j < 4; ++j) {
        int kk = g * 4 + j;
        bf16x8 af = *(const bf16x8*)&Qs[sw(l31, kk * 16 + lh8)];
        c0 = __builtin_amdgcn_mfma_f32_32x32x16_bf16(af, cur[j][0], c0, 0, 0, 0);
        c1 = __builtin_amdgcn_mfma_f32_32x32x16_bf16(af, cur[j][1], c1, 0, 0, 0);
      }
#pragma unroll
      for (int j = 0; j < 4; ++j) { cur[j][0] = nxt[j][0]; cur[j][1] = nxt[j][1]; }
    }
#pragma unroll
    for (int r = 0; r < 16; ++r) {
      float s;
      s = c0[r] * SCALE; sumv[r] += s; sqv[r] += s * s;
      s = c1[r] * SCALE; sumv[r] += s; sqv[r] += s * s;
    }
  }

  // reduce over the 32 k-lanes (each half-wave covers distinct k-cols)
#pragma unroll
  for (int r = 0; r < 16; ++r) {
    float v1 = sumv[r], v2 = sqv[r];
#pragma unroll
    for (int m = 16; m >= 1; m >>= 1) { v1 += __shfl_xor(v1, m); v2 += __shfl_xor(v2, m); }
    sumv[r] = v1; sqv[r] = v2;
  }
  if (l31 == 0) {
#pragma unroll
    for (int r = 0; r < 16; ++r) {
      scratch[w * 32 + qrow[r]]       = sumv[r];
      scratch[256 + w * 32 + qrow[r]] = sqv[r];
    }
  }
  __syncthreads();
  if (tid < 32) {
    float s = 0.f, q = 0.f;
#pragma unroll
    for (int w2 = 0; w2 < 8; ++w2) { s += scratch[w2 * 32 + tid]; q += scratch[256 + w2 * 32 + tid]; }
    float mean = s * (1.0f / 2048.0f);
    float var  = (q - 2048.0f * mean * mean) * (1.0f / 2047.0f);
    var = fmaxf(var, 0.0f);
    // p = exp((s*SCALE)*istd) up to the per-row constant exp(-mean*istd), which
    // cancels in softmax; a1 folds SCALE*istd*log2(e) for exp2.
    scratch[512 + tid] = SCALE * LOG2E / (sqrtf(var) + 1e-6f);
  }
  __syncthreads();
  float a1r[16];
#pragma unroll
  for (int r = 0; r < 16; ++r) a1r[r] = scratch[512 + qrow[r]];
  __syncthreads();  // scratch reads done before Ps is reused as the P tile

  // ================= PASS 2: softmax + PV =================
  f32x16 O0 = {}, O1 = {};   // wave w owns d in [w*64, w*64+64): two 32-col tiles
  float den = 0.f;           // per-lane: row l31, this half's k-columns

  for (int kt = 0; kt < 4; ++kt) {
    // ---- recompute scores for k-cols [kt*512 + w*64, +64) (prefetched) ----
    const bf16* Kb = Kw + ((size_t)b * SS + kt * 512 + w * 64) * DD;
    f32x16 s0 = {}, s1 = {};
    {
      bf16x8 cur[4][2], nxt[4][2];
#pragma unroll
      for (int j = 0; j < 4; ++j) {
        cur[j][0] = *(const bf16x8*)&Kb[(size_t)(l31)      * DD + j * 16 + lh8];
        cur[j][1] = *(const bf16x8*)&Kb[(size_t)(32 + l31) * DD + j * 16 + lh8];
      }
#pragma unroll
      for (int g = 0; g < 8; ++g) {
        if (g < 7) {
#pragma unroll
          for (int j = 0; j < 4; ++j) {
            int kk = (g + 1) * 4 + j;
            nxt[j][0] = *(const bf16x8*)&Kb[(size_t)(l31)      * DD + kk * 16 + lh8];
            nxt[j][1] = *(const bf16x8*)&Kb[(size_t)(32 + l31) * DD + kk * 16 + lh8];
          }
        }
#pragma unroll
        for (int j = 0; j < 4; ++j) {
          int kk = g * 4 + j;
          bf16x8 af = *(const bf16x8*)&Qs[sw(l31, kk * 16 + lh8)];
          s0 = __builtin_amdgcn_mfma_f32_32x32x16_bf16(af, cur[j][0], s0, 0, 0, 0);
          s1 = __builtin_amdgcn_mfma_f32_32x32x16_bf16(af, cur[j][1], s1, 0, 0, 0);
        }
#pragma unroll
        for (int j = 0; j < 4; ++j) { cur[j][0] = nxt[j][0]; cur[j][1] = nxt[j][1]; }
      }
    }
    __syncthreads();  // previous iteration's PV reads of Ps are done
#pragma unroll
    for (int r = 0; r < 16; ++r) {
      float p0 = exp2f(s0[r] * a1r[r]);
      float p1 = exp2f(s1[r] * a1r[r]);
      Ps[sw(qrow[r], w * 64 + l31)]      = (bf16)p0;
      Ps[sw(qrow[r], w * 64 + 32 + l31)] = (bf16)p1;
    }
    __syncthreads();  // P tile (32 x 512) complete for all waves

    // ---- PV over this 512-k chunk (V fragments prefetched) ----
    const bf16* Vb = Vw + ((size_t)b * DD + w * 64) * SS + kt * 512;
    {
      bf16x8 vcur[4][2], vnxt[4][2];
#pragma unroll
      for (int j = 0; j < 4; ++j) {
        vcur[j][0] = *(const bf16x8*)&Vb[(size_t)(l31)      * SS + j * 16 + lh8];
        vcur[j][1] = *(const bf16x8*)&Vb[(size_t)(32 + l31) * SS + j * 16 + lh8];
      }
#pragma unroll
      for (int g = 0; g < 8; ++g) {
        if (g < 7) {
#pragma unroll
          for (int j = 0; j < 4; ++j) {
            int kk = (g + 1) * 4 + j;
            vnxt[j][0] = *(const bf16x8*)&Vb[(size_t)(l31)      * SS + kk * 16 + lh8];
            vnxt[j][1] = *(const bf16x8*)&Vb[(size_t)(32 + l31) * SS + kk * 16 + lh8];
          }
        }
#pragma unroll
        for (int j = 0; j < 4; ++j) {
          int kk = g * 4 + j;
          bf16x8 pf = *(const bf16x8*)&Ps[sw(l31, kk * 16 + lh8)];
          O0 = __builtin_amdgcn_mfma_f32_32x32x16_bf16(pf, vcur[j][0], O0, 0, 0, 0);
          O1 = __builtin_amdgcn_mfma_f32_32x32x16_bf16(pf, vcur[j][1], O1, 0, 0, 0);
          // denominator from the same bf16 P values the numerator uses
          union { bf16x8 h; unsigned u[4]; } cv; cv.h = pf;
#pragma unroll
          for (int jj = 0; jj < 4; ++jj) {
            den += __uint_as_float(cv.u[jj] << 16) + __uint_as_float(cv.u[jj] & 0xffff0000u);
          }
        }
#pragma unroll
        for (int j = 0; j < 4; ++j) { vcur[j][0] = vnxt[j][0]; vcur[j][1] = vnxt[j][1]; }
      }
    }
    __syncthreads();  // PV reads done before next kt overwrites Ps
  }

  // den: combine the two lane-halves -> every lane has full row-l31 denominator
  den += __shfl_xor(den, 32);
  if (tid < 32) scratch[tid] = 1.0f / den;   // lanes 0..31: row = l31 = tid
  __syncthreads();
  float idr[16];
#pragma unroll
  for (int r = 0; r < 16; ++r) idr[r] = scratch[qrow[r]];

  float* Ob = Op + ((size_t)b * SS + q0) * DD + w * 64;
#pragma unroll
  for (int r = 0; r < 16; ++r) {
    Ob[(size_t)qrow[r] * DD + l31]      = O0[r] * idr[r];
    Ob[(size_t)qrow[r] * DD + 32 + l31] = O1[r] * idr[r];
  }
}

// ---------------- fallback (round-1 kernel, zero workspace) ----------------

#define QS_STRIDE 520
#define KS_STRIDE 72
#define VT_STRIDE 18
#define PS_STRIDE 136

__device__ __forceinline__ f32x16 qk_tile(const float* __restrict__ Kb,
                                          const bf16* __restrict__ Qsl,
                                          bf16* __restrict__ KVw,
                                          int l31, int lh8, int lane) {
  f32x16 acc = {};
  for (int dc = 0; dc < DD; dc += 64) {
#pragma unroll
    for (int i = 0; i < 8; ++i) {
      int f = i * 64 + lane;
      int row = f >> 4;
      int c4 = (f & 15) * 4;
      float4 v = *(const float4*)(Kb + row * DD + dc + c4);
      bf16x4 h = { (bf16)v.x, (bf16)v.y, (bf16)v.z, (bf16)v.w };
      *(bf16x4*)&KVw[row * KS_STRIDE + c4] = h;
    }
#pragma unroll
    for (int ks = 0; ks < 4; ++ks) {
      bf16x8 a  = *(const bf16x8*)&Qsl[l31 * QS_STRIDE + dc + ks * 16 + lh8];
      bf16x8 bb = *(const bf16x8*)&KVw[l31 * KS_STRIDE + ks * 16 + lh8];
      acc = __builtin_amdgcn_mfma_f32_32x32x16_bf16(a, bb, acc, 0, 0, 0);
    }
  }
  return acc;
}

__launch_bounds__(256, 1)
__global__ void nm_attn_kernel(const float* __restrict__ Qp,
                               const float* __restrict__ Kp,
                               const float* __restrict__ Vp,
                               float* __restrict__ Op) {
  __shared__ bf16 Qs[32 * QS_STRIDE];
  __shared__ bf16 KVu[4][32 * KS_STRIDE];
  __shared__ bf16 Psl[32 * PS_STRIDE];
  __shared__ float redA[4][32];
  __shared__ float redB[4][32];
  __shared__ float a0v[32], a1v[32], idv[32];

  const int tid  = threadIdx.x;
  const int w    = tid >> 6;
  const int lane = tid & 63;
  const int l31  = lane & 31;
  const int lh8  = (lane >> 5) * 8;
  const int b    = blockIdx.y;
  const int q0   = blockIdx.x * 32;

  {
    const float* Qbase = Qp + (size_t)(b * SS + q0) * DD;
#pragma unroll
    for (int i = 0; i < 16; ++i) {
      int f = i * 256 + tid;
      int row = f >> 7;
      int c4 = (f & 127) * 4;
      float4 v = *(const float4*)(Qbase + row * DD + c4);
      bf16x4 h = { (bf16)v.x, (bf16)v.y, (bf16)v.z, (bf16)v.w };
      *(bf16x4*)&Qs[row * QS_STRIDE + c4] = h;
    }
  }
  __syncthreads();

  int qrow[16];
#pragma unroll
  for (int r = 0; r < 16; ++r) qrow[r] = (r & 3) + 8 * (r >> 2) + 4 * (lane >> 5);

  float sumv[16], sqv[16];
#pragma unroll
  for (int r = 0; r < 16; ++r) { sumv[r] = 0.f; sqv[r] = 0.f; }

  for (int kt = 0; kt < 16; ++kt) {
    const float* Kb = Kp + (size_t)(b * SS + kt * 128 + w * 32) * DD;
    f32x16 acc = qk_tile(Kb, Qs, KVu[w], l31, lh8, lane);
#pragma unroll
    for (int r = 0; r < 16; ++r) {
      float s = acc[r] * SCALE;
      sumv[r] += s;
      sqv[r]  += s * s;
    }
  }

#pragma unroll
  for (int r = 0; r < 16; ++r) {
    float v1 = sumv[r], v2 = sqv[r];
#pragma unroll
    for (int m = 16; m >= 1; m >>= 1) {
      v1 += __shfl_xor(v1, m);
      v2 += __shfl_xor(v2, m);
    }
    if (l31 == 0) { redA[w][qrow[r]] = v1; redB[w][qrow[r]] = v2; }
  }
  __syncthreads();
  if (tid < 32) {
    float s  = redA[0][tid] + redA[1][tid] + redA[2][tid] + redA[3][tid];
    float sq = redB[0][tid] + redB[1][tid] + redB[2][tid] + redB[3][tid];
    float mean = s * (1.0f / 2048.0f);
    float var = (sq - 2048.0f * mean * mean) * (1.0f / 2047.0f);
    var = fmaxf(var, 0.0f);
    float istd = 1.0f / (sqrtf(var) + 1e-6f);
    a1v[tid] = istd * LOG2E;
    a0v[tid] = -mean * istd * LOG2E;
  }
  __syncthreads();

  float a0r[16], a1r[16], den[16];
#pragma unroll
  for (int r = 0; r < 16; ++r) {
    a0r[r] = a0v[qrow[r]];
    a1r[r] = a1v[qrow[r]];
    den[r] = 0.f;
  }

  f32x16 Oa[4] = {};

  for (int kt = 0; kt < 16; ++kt) {
    const float* Kb = Kp + (size_t)(b * SS + kt * 128 + w * 32) * DD;
    f32x16 acc = qk_tile(Kb, Qs, KVu[w], l31, lh8, lane);

    __syncthreads();
#pragma unroll
    for (int r = 0; r < 16; ++r) {
      float s = acc[r] * SCALE;
      float p = exp2f(fmaf(s, a1r[r], a0r[r]));
      den[r] += p;
      Psl[qrow[r] * PS_STRIDE + w * 32 + l31] = (bf16)p;
    }
    __syncthreads();

    const float* Vb = Vp + (size_t)(b * SS + kt * 128) * DD + w * 128 + 2 * lane;
    bf16* Vt = KVu[w];
    const int d0 = 2 * lane;
    for (int ks2 = 0; ks2 < 8; ++ks2) {
      const float* Vk = Vb + ks2 * 16 * DD;
#pragma unroll
      for (int i = 0; i < 8; ++i) {
        float2 va = *(const float2*)(Vk + (2 * i) * DD);
        float2 vc = *(const float2*)(Vk + (2 * i + 1) * DD);
        bf16x2 h0 = { (bf16)va.x, (bf16)vc.x };
        bf16x2 h1 = { (bf16)va.y, (bf16)vc.y };
        *(bf16x2*)&Vt[d0 * VT_STRIDE + 2 * i] = h0;
        *(bf16x2*)&Vt[(d0 + 1) * VT_STRIDE + 2 * i] = h1;
      }
      bf16x8 aP = *(const bf16x8*)&Psl[l31 * PS_STRIDE + ks2 * 16 + lh8];
#pragma unroll
      for (int dt = 0; dt < 4; ++dt) {
        const bf16* vr = &Vt[(dt * 32 + l31) * VT_STRIDE + lh8];
        bf16x2 e0 = *(const bf16x2*)(vr + 0);
        bf16x2 e1 = *(const bf16x2*)(vr + 2);
        bf16x2 e2 = *(const bf16x2*)(vr + 4);
        bf16x2 e3 = *(const bf16x2*)(vr + 6);
        bf16x8 bV = { e0.x, e0.y, e1.x, e1.y, e2.x, e2.y, e3.x, e3.y };
        Oa[dt] = __builtin_amdgcn_mfma_f32_32x32x16_bf16(aP, bV, Oa[dt], 0, 0, 0);
      }
    }
  }

#pragma unroll
  for (int r = 0; r < 16; ++r) {
    float v1 = den[r];
#pragma unroll
    for (int m = 16; m >= 1; m >>= 1) v1 += __shfl_xor(v1, m);
    if (l31 == 0) redA[w][qrow[r]] = v1;
  }
  __syncthreads();
  if (tid < 32) {
    float t = redA[0][tid] + redA[1][tid] + redA[2][tid] + redA[3][tid];
    idv[tid] = 1.0f / t;
  }
  __syncthreads();

  float idr[16];
#pragma unroll
  for (int r = 0; r < 16; ++r) idr[r] = idv[qrow[r]];

  float* Ob = Op + (size_t)(b * SS + q0) * DD + w * 128;
#pragma unroll
  for (int dt = 0; dt < 4; ++dt) {
#pragma unroll
    for (int r = 0; r < 16; ++r) {
      Ob[qrow[r] * DD + dt * 32 + l31] = Oa[dt][r] * idr[r];
    }
  }
}

// ---------------- launcher ----------------

extern "C" void kernel_launch(void* const* d_in, const int* in_sizes, int n_in,
                              void* d_out, int out_size, void* d_ws, size_t ws_size,
                              hipStream_t stream) {
  const float* Q = (const float*)d_in[0];
  const float* K = (const float*)d_in[1];
  const float* V = (const float*)d_in[2];
  float* out = (float*)d_out;
  (void)in_sizes; (void)n_in; (void)out_size;

  const size_t elems = (size_t)BB * SS * DD;           // 4,194,304
  const size_t need  = 3 * elems * sizeof(bf16);       // 25,165,824 B

  if (ws_size >= need) {
    bf16* Kb = (bf16*)d_ws;
    bf16* Qb = Kb + elems;
    bf16* Vt = Qb + elems;
    cast_qk_kernel<<<(int)(elems / 8 / 256), 256, 0, stream>>>(Q, K, Qb, Kb);
    transpose_v_kernel<<<dim3(SS / 64, DD / 64, BB), 256, 0, stream>>>(V, Vt);
    nm_attn3_kernel<<<256, 512, 0, stream>>>(Qb, Kb, Vt, out);
  } else {
    nm_attn_kernel<<<dim3(SS / 32, BB), dim3(256, 1, 1), 0, stream>>>(Q, K, V, out);
  }
}

// Round 4
// 272.558 us; speedup vs baseline: 1.2170x; 1.2170x over previous
//
#include <hip/hip_runtime.h>

// NeuromodulatedAttention — MI355X (gfx950), round 4
//
// ALGEBRA: (1) dopamine/serotonin "mod" is a per-row constant added before the
// per-row mean/std normalization -> cancels exactly (both MLPs are dead code).
// (2) the mean subtraction is a per-row constant inside softmax -> also cancels.
// Effective:  out = softmax( S * istd_row ) @ V,
//   S = Q K^T / sqrt(512),  istd_row = 1/(std(S_row, ddof=1) + 1e-6).
//
// Round-4: rounds 2-3 were structurally latency-bound (1 block/CU, 8 waves,
// per-kt barrier convoys; round-3 prefetch spilled under launch_bounds(512,2)).
// New structure: k-split 3-phase pipeline, 1024 blocks everywhere (4 blocks/CU,
// 16 waves/CU), one barrier pair per block, S materialized in fp16 (no QK
// recompute), private fp32 partials (no output atomics), tiny stats/den atomics.

#define BB 4
#define SS 2048
#define DD 512
#define SCALE 0.044194173824159216f  // 1/sqrt(512)
#define LOG2E 1.4426950408889634f

typedef __bf16 bf16;
typedef _Float16 f16;
typedef bf16 bf16x2 __attribute__((ext_vector_type(2)));
typedef bf16 bf16x4 __attribute__((ext_vector_type(4)));
typedef bf16 bf16x8 __attribute__((ext_vector_type(8)));
typedef f16  f16x8  __attribute__((ext_vector_type(8)));
typedef float f32x16 __attribute__((ext_vector_type(16)));

// XOR-swizzled element index inside a 32x512 bf16 LDS tile.
__device__ __forceinline__ int sw(int row, int col) {
  return row * 512 + ((((col >> 3) ^ (row & 7))) << 3) + (col & 7);
}

// ---------------- K1: precast ----------------

__global__ void cast_qk_kernel(const float* __restrict__ Q, const float* __restrict__ K,
                               bf16* __restrict__ Qb, bf16* __restrict__ Kb) {
  size_t i = ((size_t)blockIdx.x * 256 + threadIdx.x) * 8;
  float4 a0 = *(const float4*)(Q + i);
  float4 a1 = *(const float4*)(Q + i + 4);
  bf16x8 qa = { (bf16)a0.x, (bf16)a0.y, (bf16)a0.z, (bf16)a0.w,
                (bf16)a1.x, (bf16)a1.y, (bf16)a1.z, (bf16)a1.w };
  *(bf16x8*)(Qb + i) = qa;
  float4 b0 = *(const float4*)(K + i);
  float4 b1 = *(const float4*)(K + i + 4);
  bf16x8 ka = { (bf16)b0.x, (bf16)b0.y, (bf16)b0.z, (bf16)b0.w,
                (bf16)b1.x, (bf16)b1.y, (bf16)b1.z, (bf16)b1.w };
  *(bf16x8*)(Kb + i) = ka;
}

// V [b][s][d] fp32 -> Vt [b][d][s] bf16. 64x64 tiles, 256 threads.
__global__ void transpose_v_kernel(const float* __restrict__ V, bf16* __restrict__ Vt) {
  __shared__ bf16 tile[64][80];
  const int b = blockIdx.z;
  const int s0 = blockIdx.x * 64, d0 = blockIdx.y * 64;
  const int t = threadIdx.x;
  const int r16 = t >> 4;
  const int c4  = (t & 15) * 4;
#pragma unroll
  for (int i = 0; i < 4; ++i) {
    int r = i * 16 + r16;
    float4 v = *(const float4*)&V[((size_t)b * SS + s0 + r) * DD + d0 + c4];
    tile[c4 + 0][r] = (bf16)v.x;
    tile[c4 + 1][r] = (bf16)v.y;
    tile[c4 + 2][r] = (bf16)v.z;
    tile[c4 + 3][r] = (bf16)v.w;
  }
  __syncthreads();
  const int dr8 = t >> 3;
  const int sc8 = (t & 7) * 8;
#pragma unroll
  for (int i = 0; i < 2; ++i) {
    int dr = i * 32 + dr8;
    bf16x8 o = *(const bf16x8*)&tile[dr][sc8];
    *(bf16x8*)&Vt[((size_t)b * DD + d0 + dr) * SS + s0 + sc8] = o;
  }
}

// ---------------- K2: QK -> S (fp16) + row stats ----------------
// grid (64 qt, 4 kc, 4 b), 256 thr (4 waves). Wave w: k-cols [kc*512+w*128, +128).

__launch_bounds__(256, 4)
__global__ void stats_kernel(const bf16* __restrict__ Qw, const bf16* __restrict__ Kw,
                             f16* __restrict__ Sp, float* __restrict__ stats) {
  __shared__ bf16 Qs[32 * 512];
  __shared__ float red[4][2][32];

  const int tid  = threadIdx.x;
  const int w    = tid >> 6;
  const int lane = tid & 63;
  const int l31  = lane & 31;
  const int lh8  = (lane >> 5) * 8;
  const int qt = blockIdx.x, kc = blockIdx.y, b = blockIdx.z;
  const int q0 = qt * 32;
  const int k0 = kc * 512 + w * 128;

  // stage Q tile (32 x 512 bf16) swizzled
  {
    const bf16* Qb = Qw + ((size_t)b * SS + q0) * DD;
#pragma unroll
    for (int i = 0; i < 8; ++i) {
      int f = i * 256 + tid;
      int row = f >> 6, g = f & 63;
      bf16x8 v = *(const bf16x8*)&Qb[(size_t)row * DD + g * 8];
      *(bf16x8*)&Qs[row * 512 + ((g ^ (row & 7)) << 3)] = v;
    }
  }
  __syncthreads();

  int qrow[16];
#pragma unroll
  for (int r = 0; r < 16; ++r) qrow[r] = (r & 3) + 8 * (r >> 2) + 4 * (lane >> 5);

  // QK with double-buffered B-fragments (4 rows x 16B in flight per wave)
  const bf16* Kb = Kw + ((size_t)b * SS + k0) * DD;
  f32x16 acc0 = {}, acc1 = {}, acc2 = {}, acc3 = {};
  bf16x8 c0, c1, c2, c3;
  c0 = *(const bf16x8*)&Kb[(size_t)(l31)      * DD + lh8];
  c1 = *(const bf16x8*)&Kb[(size_t)(32 + l31) * DD + lh8];
  c2 = *(const bf16x8*)&Kb[(size_t)(64 + l31) * DD + lh8];
  c3 = *(const bf16x8*)&Kb[(size_t)(96 + l31) * DD + lh8];
#pragma unroll 8
  for (int kk = 0; kk < 32; ++kk) {
    bf16x8 n0, n1, n2, n3;
    if (kk < 31) {
      int o = (kk + 1) * 16 + lh8;
      n0 = *(const bf16x8*)&Kb[(size_t)(l31)      * DD + o];
      n1 = *(const bf16x8*)&Kb[(size_t)(32 + l31) * DD + o];
      n2 = *(const bf16x8*)&Kb[(size_t)(64 + l31) * DD + o];
      n3 = *(const bf16x8*)&Kb[(size_t)(96 + l31) * DD + o];
    }
    bf16x8 af = *(const bf16x8*)&Qs[sw(l31, kk * 16 + lh8)];
    acc0 = __builtin_amdgcn_mfma_f32_32x32x16_bf16(af, c0, acc0, 0, 0, 0);
    acc1 = __builtin_amdgcn_mfma_f32_32x32x16_bf16(af, c1, acc1, 0, 0, 0);
    acc2 = __builtin_amdgcn_mfma_f32_32x32x16_bf16(af, c2, acc2, 0, 0, 0);
    acc3 = __builtin_amdgcn_mfma_f32_32x32x16_bf16(af, c3, acc3, 0, 0, 0);
    c0 = n0; c1 = n1; c2 = n2; c3 = n3;
  }

  // write S (fp16) + accumulate per-row stats
  f16* Sb = Sp + ((size_t)b * SS + q0) * SS + k0;
  float sumv[16], sqv[16];
#pragma unroll
  for (int r = 0; r < 16; ++r) {
    float s0 = acc0[r] * SCALE, s1 = acc1[r] * SCALE;
    float s2 = acc2[r] * SCALE, s3 = acc3[r] * SCALE;
    f16* Sr = Sb + (size_t)qrow[r] * SS;
    Sr[l31]      = (f16)s0;
    Sr[32 + l31] = (f16)s1;
    Sr[64 + l31] = (f16)s2;
    Sr[96 + l31] = (f16)s3;
    sumv[r] = s0 + s1 + s2 + s3;
    sqv[r]  = s0 * s0 + s1 * s1 + s2 * s2 + s3 * s3;
  }
#pragma unroll
  for (int r = 0; r < 16; ++r) {
    float v1 = sumv[r], v2 = sqv[r];
#pragma unroll
    for (int m = 16; m >= 1; m >>= 1) { v1 += __shfl_xor(v1, m); v2 += __shfl_xor(v2, m); }
    if (l31 == 0) { red[w][0][qrow[r]] = v1; red[w][1][qrow[r]] = v2; }
  }
  __syncthreads();
  if (tid < 32) {
    float s = red[0][0][tid] + red[1][0][tid] + red[2][0][tid] + red[3][0][tid];
    float q = red[0][1][tid] + red[1][1][tid] + red[2][1][tid] + red[3][1][tid];
    atomicAdd(&stats[b * SS + q0 + tid], s);
    atomicAdd(&stats[BB * SS + b * SS + q0 + tid], q);
  }
}

// ---------------- K3: softmax + PV partial ----------------
// grid (64 qt, 4 kc, 4 b), 256 thr (4 waves). Wave w: d-range [w*128, +128).

__launch_bounds__(256, 4)
__global__ void pv_kernel(const f16* __restrict__ Sp, const float* __restrict__ stats,
                          const bf16* __restrict__ Vt, float* __restrict__ Opart,
                          float* __restrict__ den) {
  __shared__ bf16 Ps[32 * 512];
  __shared__ float a1s[32];
  __shared__ float dscr[32];

  const int tid  = threadIdx.x;
  const int w    = tid >> 6;
  const int lane = tid & 63;
  const int l31  = lane & 31;
  const int lh8  = (lane >> 5) * 8;
  const int qt = blockIdx.x, kc = blockIdx.y, b = blockIdx.z;
  const int q0 = qt * 32;
  const int k0 = kc * 512;

  if (tid < 32) {
    float s  = stats[b * SS + q0 + tid];
    float sq = stats[BB * SS + b * SS + q0 + tid];
    float mean = s * (1.0f / 2048.0f);
    float var  = (sq - 2048.0f * mean * mean) * (1.0f / 2047.0f);
    var = fmaxf(var, 0.0f);
    // p = exp((s - mean)*istd); the exp(-mean*istd) factor is per-row and
    // cancels in softmax, so exponent = s * istd (log2-folded).
    a1s[tid]  = LOG2E / (sqrtf(var) + 1e-6f);
    dscr[tid] = 0.f;
  }
  __syncthreads();

  // build P tile: read S fp16, exp2, store bf16 swizzled; accumulate den
  {
    const f16* Sb = Sp + ((size_t)b * SS + q0) * SS + k0;
#pragma unroll
    for (int i = 0; i < 8; ++i) {
      int f = i * 256 + tid;
      int row = f >> 6, g = f & 63;
      f16x8 hv = *(const f16x8*)&Sb[(size_t)row * SS + g * 8];
      float a1 = a1s[row];
      bf16x8 pb;
      float loc = 0.f;
#pragma unroll
      for (int j = 0; j < 8; ++j) {
        float p = exp2f((float)hv[j] * a1);
        bf16 pc = (bf16)p;
        pb[j] = pc;
        loc += (float)pc;   // denominator from the same bf16 values PV uses
      }
      *(bf16x8*)&Ps[row * 512 + ((g ^ (row & 7)) << 3)] = pb;
      atomicAdd(&dscr[row], loc);
    }
  }
  __syncthreads();
  if (tid < 32) atomicAdd(&den[b * SS + q0 + tid], dscr[tid]);

  int qrow[16];
#pragma unroll
  for (int r = 0; r < 16; ++r) qrow[r] = (r & 3) + 8 * (r >> 2) + 4 * (lane >> 5);

  // PV with double-buffered Vt B-fragments
  const bf16* Vb = Vt + ((size_t)b * DD + w * 128) * SS + k0;
  f32x16 acc0 = {}, acc1 = {}, acc2 = {}, acc3 = {};
  bf16x8 c0, c1, c2, c3;
  c0 = *(const bf16x8*)&Vb[(size_t)(l31)      * SS + lh8];
  c1 = *(const bf16x8*)&Vb[(size_t)(32 + l31) * SS + lh8];
  c2 = *(const bf16x8*)&Vb[(size_t)(64 + l31) * SS + lh8];
  c3 = *(const bf16x8*)&Vb[(size_t)(96 + l31) * SS + lh8];
#pragma unroll 8
  for (int kk = 0; kk < 32; ++kk) {
    bf16x8 n0, n1, n2, n3;
    if (kk < 31) {
      int o = (kk + 1) * 16 + lh8;
      n0 = *(const bf16x8*)&Vb[(size_t)(l31)      * SS + o];
      n1 = *(const bf16x8*)&Vb[(size_t)(32 + l31) * SS + o];
      n2 = *(const bf16x8*)&Vb[(size_t)(64 + l31) * SS + o];
      n3 = *(const bf16x8*)&Vb[(size_t)(96 + l31) * SS + o];
    }
    bf16x8 pf = *(const bf16x8*)&Ps[sw(l31, kk * 16 + lh8)];
    acc0 = __builtin_amdgcn_mfma_f32_32x32x16_bf16(pf, c0, acc0, 0, 0, 0);
    acc1 = __builtin_amdgcn_mfma_f32_32x32x16_bf16(pf, c1, acc1, 0, 0, 0);
    acc2 = __builtin_amdgcn_mfma_f32_32x32x16_bf16(pf, c2, acc2, 0, 0, 0);
    acc3 = __builtin_amdgcn_mfma_f32_32x32x16_bf16(pf, c3, acc3, 0, 0, 0);
    c0 = n0; c1 = n1; c2 = n2; c3 = n3;
  }

  // store private partial (no atomics): Opart[kc][b][q][d]
  float* Ob = Opart + (size_t)kc * (BB * SS * DD) + ((size_t)b * SS + q0) * DD + w * 128;
#pragma unroll
  for (int r = 0; r < 16; ++r) {
    float* Or = Ob + (size_t)qrow[r] * DD;
    Or[l31]      = acc0[r];
    Or[32 + l31] = acc1[r];
    Or[64 + l31] = acc2[r];
    Or[96 + l31] = acc3[r];
  }
}

// ---------------- K4: reduce partials / denominator ----------------

__global__ void reduce_kernel(const float* __restrict__ Opart,
                              const float* __restrict__ den,
                              float* __restrict__ out) {
  const size_t E = (size_t)BB * SS * DD;
  size_t idx = ((size_t)blockIdx.x * 256 + threadIdx.x) * 4;
  float4 a = *(const float4*)(Opart + idx);
  float4 b = *(const float4*)(Opart + E + idx);
  float4 c = *(const float4*)(Opart + 2 * E + idx);
  float4 d = *(const float4*)(Opart + 3 * E + idx);
  float inv = 1.0f / den[idx >> 9];
  float4 o = { (a.x + b.x + c.x + d.x) * inv,
               (a.y + b.y + c.y + d.y) * inv,
               (a.z + b.z + c.z + d.z) * inv,
               (a.w + b.w + c.w + d.w) * inv };
  *(float4*)(out + idx) = o;
}

// ---------------- middle path: round-3 fused kernel, spill fix ----------------

__launch_bounds__(512, 1)
__global__ void nm_attn3_kernel(const bf16* __restrict__ Qw,
                                const bf16* __restrict__ Kw,
                                const bf16* __restrict__ Vw,
                                float* __restrict__ Op) {
  __shared__ bf16 Qs[32 * 512];
  __shared__ bf16 Ps[32 * 512];
  float* scratch = (float*)Ps;

  const int tid  = threadIdx.x;
  const int w    = tid >> 6;
  const int lane = tid & 63;
  const int l31  = lane & 31;
  const int lh8  = (lane >> 5) * 8;
  const int bid  = blockIdx.x;
  const int b  = (bid & 7) >> 1;
  const int qt = ((bid >> 3) << 1) | (bid & 1);
  const int q0 = qt * 32;

  {
    const bf16* Qb = Qw + ((size_t)b * SS + q0) * DD;
#pragma unroll
    for (int i = 0; i < 4; ++i) {
      int f = i * 512 + tid;
      int row = f >> 6, g = f & 63;
      bf16x8 v = *(const bf16x8*)&Qb[(size_t)row * DD + g * 8];
      *(bf16x8*)&Qs[row * 512 + ((g ^ (row & 7)) << 3)] = v;
    }
  }
  __syncthreads();

  int qrow[16];
#pragma unroll
  for (int r = 0; r < 16; ++r) qrow[r] = (r & 3) + 8 * (r >> 2) + 4 * (lane >> 5);

  float sumv[16], sqv[16];
#pragma unroll
  for (int r = 0; r < 16; ++r) { sumv[r] = 0.f; sqv[r] = 0.f; }

  for (int kt = 0; kt < 4; ++kt) {
    const bf16* Kb = Kw + ((size_t)b * SS + kt * 512 + w * 64) * DD;
    f32x16 acc0 = {}, acc1 = {};
    bf16x8 c0, c1;
    c0 = *(const bf16x8*)&Kb[(size_t)(l31)      * DD + lh8];
    c1 = *(const bf16x8*)&Kb[(size_t)(32 + l31) * DD + lh8];
#pragma unroll 8
    for (int kk = 0; kk < 32; ++kk) {
      bf16x8 n0, n1;
      if (kk < 31) {
        int o = (kk + 1) * 16 + lh8;
        n0 = *(const bf16x8*)&Kb[(size_t)(l31)      * DD + o];
        n1 = *(const bf16x8*)&Kb[(size_t)(32 + l31) * DD + o];
      }
      bf16x8 af = *(const bf16x8*)&Qs[sw(l31, kk * 16 + lh8)];
      acc0 = __builtin_amdgcn_mfma_f32_32x32x16_bf16(af, c0, acc0, 0, 0, 0);
      acc1 = __builtin_amdgcn_mfma_f32_32x32x16_bf16(af, c1, acc1, 0, 0, 0);
      c0 = n0; c1 = n1;
    }
#pragma unroll
    for (int r = 0; r < 16; ++r) {
      float s;
      s = acc0[r] * SCALE; sumv[r] += s; sqv[r] += s * s;
      s = acc1[r] * SCALE; sumv[r] += s; sqv[r] += s * s;
    }
  }

#pragma unroll
  for (int r = 0; r < 16; ++r) {
    float v1 = sumv[r], v2 = sqv[r];
#pragma unroll
    for (int m = 16; m >= 1; m >>= 1) { v1 += __shfl_xor(v1, m); v2 += __shfl_xor(v2, m); }
    sumv[r] = v1; sqv[r] = v2;
  }
  if (l31 == 0) {
#pragma unroll
    for (int r = 0; r < 16; ++r) {
      scratch[w * 32 + qrow[r]]       = sumv[r];
      scratch[256 + w * 32 + qrow[r]] = sqv[r];
    }
  }
  __syncthreads();
  if (tid < 32) {
    float s = 0.f, q = 0.f;
#pragma unroll
    for (int w2 = 0; w2 < 8; ++w2) { s += scratch[w2 * 32 + tid]; q += scratch[256 + w2 * 32 + tid]; }
    float mean = s * (1.0f / 2048.0f);
    float var  = (q - 2048.0f * mean * mean) * (1.0f / 2047.0f);
    var = fmaxf(var, 0.0f);
    scratch[512 + tid] = SCALE * LOG2E / (sqrtf(var) + 1e-6f);
  }
  __syncthreads();
  float a1r[16];
#pragma unroll
  for (int r = 0; r < 16; ++r) a1r[r] = scratch[512 + qrow[r]];
  __syncthreads();

  f32x16 O0 = {}, O1 = {};
  float den = 0.f;

  for (int kt = 0; kt < 4; ++kt) {
    const bf16* Kb = Kw + ((size_t)b * SS + kt * 512 + w * 64) * DD;
    f32x16 s0 = {}, s1 = {};
    {
      bf16x8 c0, c1;
      c0 = *(const bf16x8*)&Kb[(size_t)(l31)      * DD + lh8];
      c1 = *(const bf16x8*)&Kb[(size_t)(32 + l31) * DD + lh8];
#pragma unroll 8
      for (int kk = 0; kk < 32; ++kk) {
        bf16x8 n0, n1;
        if (kk < 31) {
          int o = (kk + 1) * 16 + lh8;
          n0 = *(const bf16x8*)&Kb[(size_t)(l31)      * DD + o];
          n1 = *(const bf16x8*)&Kb[(size_t)(32 + l31) * DD + o];
        }
        bf16x8 af = *(const bf16x8*)&Qs[sw(l31, kk * 16 + lh8)];
        s0 = __builtin_amdgcn_mfma_f32_32x32x16_bf16(af, c0, s0, 0, 0, 0);
        s1 = __builtin_amdgcn_mfma_f32_32x32x16_bf16(af, c1, s1, 0, 0, 0);
        c0 = n0; c1 = n1;
      }
    }
    __syncthreads();
#pragma unroll
    for (int r = 0; r < 16; ++r) {
      float p0 = exp2f(s0[r] * a1r[r]);
      float p1 = exp2f(s1[r] * a1r[r]);
      Ps[sw(qrow[r], w * 64 + l31)]      = (bf16)p0;
      Ps[sw(qrow[r], w * 64 + 32 + l31)] = (bf16)p1;
    }
    __syncthreads();

    const bf16* Vb = Vw + ((size_t)b * DD + w * 64) * SS + kt * 512;
    {
      bf16x8 c0, c1;
      c0 = *(const bf16x8*)&Vb[(size_t)(l31)      * SS + lh8];
      c1 = *(const bf16x8*)&Vb[(size_t)(32 + l31) * SS + lh8];
#pragma unroll 8
      for (int kk = 0; kk < 32; ++kk) {
        bf16x8 n0, n1;
        if (kk < 31) {
          int o = (kk + 1) * 16 + lh8;
          n0 = *(const bf16x8*)&Vb[(size_t)(l31)      * SS + o];
          n1 = *(const bf16x8*)&Vb[(size_t)(32 + l31) * SS + o];
        }
        bf16x8 pf = *(const bf16x8*)&Ps[sw(l31, kk * 16 + lh8)];
        O0 = __builtin_amdgcn_mfma_f32_32x32x16_bf16(pf, c0, O0, 0, 0, 0);
        O1 = __builtin_amdgcn_mfma_f32_32x32x16_bf16(pf, c1, O1, 0, 0, 0);
        union { bf16x8 h; unsigned u[4]; } cv; cv.h = pf;
#pragma unroll
        for (int jj = 0; jj < 4; ++jj) {
          den += __uint_as_float(cv.u[jj] << 16) + __uint_as_float(cv.u[jj] & 0xffff0000u);
        }
        c0 = n0; c1 = n1;
      }
    }
    __syncthreads();
  }

  den += __shfl_xor(den, 32);
  if (tid < 32) scratch[tid] = 1.0f / den;
  __syncthreads();
  float idr[16];
#pragma unroll
  for (int r = 0; r < 16; ++r) idr[r] = scratch[qrow[r]];

  float* Ob = Op + ((size_t)b * SS + q0) * DD + w * 64;
#pragma unroll
  for (int r = 0; r < 16; ++r) {
    Ob[(size_t)qrow[r] * DD + l31]      = O0[r] * idr[r];
    Ob[(size_t)qrow[r] * DD + 32 + l31] = O1[r] * idr[r];
  }
}

// ---------------- fallback (round-1 kernel, zero workspace) ----------------

#define QS_STRIDE 520
#define KS_STRIDE 72
#define VT_STRIDE 18
#define PS_STRIDE 136

__device__ __forceinline__ f32x16 qk_tile(const float* __restrict__ Kb,
                                          const bf16* __restrict__ Qsl,
                                          bf16* __restrict__ KVw,
                                          int l31, int lh8, int lane) {
  f32x16 acc = {};
  for (int dc = 0; dc < DD; dc += 64) {
#pragma unroll
    for (int i = 0; i < 8; ++i) {
      int f = i * 64 + lane;
      int row = f >> 4;
      int c4 = (f & 15) * 4;
      float4 v = *(const float4*)(Kb + row * DD + dc + c4);
      bf16x4 h = { (bf16)v.x, (bf16)v.y, (bf16)v.z, (bf16)v.w };
      *(bf16x4*)&KVw[row * KS_STRIDE + c4] = h;
    }
#pragma unroll
    for (int ks = 0; ks < 4; ++ks) {
      bf16x8 a  = *(const bf16x8*)&Qsl[l31 * QS_STRIDE + dc + ks * 16 + lh8];
      bf16x8 bb = *(const bf16x8*)&KVw[l31 * KS_STRIDE + ks * 16 + lh8];
      acc = __builtin_amdgcn_mfma_f32_32x32x16_bf16(a, bb, acc, 0, 0, 0);
    }
  }
  return acc;
}

__launch_bounds__(256, 1)
__global__ void nm_attn_kernel(const float* __restrict__ Qp,
                               const float* __restrict__ Kp,
                               const float* __restrict__ Vp,
                               float* __restrict__ Op) {
  __shared__ bf16 Qs[32 * QS_STRIDE];
  __shared__ bf16 KVu[4][32 * KS_STRIDE];
  __shared__ bf16 Psl[32 * PS_STRIDE];
  __shared__ float redA[4][32];
  __shared__ float redB[4][32];
  __shared__ float a0v[32], a1v[32], idv[32];

  const int tid  = threadIdx.x;
  const int w    = tid >> 6;
  const int lane = tid & 63;
  const int l31  = lane & 31;
  const int lh8  = (lane >> 5) * 8;
  const int b    = blockIdx.y;
  const int q0   = blockIdx.x * 32;

  {
    const float* Qbase = Qp + (size_t)(b * SS + q0) * DD;
#pragma unroll
    for (int i = 0; i < 16; ++i) {
      int f = i * 256 + tid;
      int row = f >> 7;
      int c4 = (f & 127) * 4;
      float4 v = *(const float4*)(Qbase + row * DD + c4);
      bf16x4 h = { (bf16)v.x, (bf16)v.y, (bf16)v.z, (bf16)v.w };
      *(bf16x4*)&Qs[row * QS_STRIDE + c4] = h;
    }
  }
  __syncthreads();

  int qrow[16];
#pragma unroll
  for (int r = 0; r < 16; ++r) qrow[r] = (r & 3) + 8 * (r >> 2) + 4 * (lane >> 5);

  float sumv[16], sqv[16];
#pragma unroll
  for (int r = 0; r < 16; ++r) { sumv[r] = 0.f; sqv[r] = 0.f; }

  for (int kt = 0; kt < 16; ++kt) {
    const float* Kb = Kp + (size_t)(b * SS + kt * 128 + w * 32) * DD;
    f32x16 acc = qk_tile(Kb, Qs, KVu[w], l31, lh8, lane);
#pragma unroll
    for (int r = 0; r < 16; ++r) {
      float s = acc[r] * SCALE;
      sumv[r] += s;
      sqv[r]  += s * s;
    }
  }

#pragma unroll
  for (int r = 0; r < 16; ++r) {
    float v1 = sumv[r], v2 = sqv[r];
#pragma unroll
    for (int m = 16; m >= 1; m >>= 1) {
      v1 += __shfl_xor(v1, m);
      v2 += __shfl_xor(v2, m);
    }
    if (l31 == 0) { redA[w][qrow[r]] = v1; redB[w][qrow[r]] = v2; }
  }
  __syncthreads();
  if (tid < 32) {
    float s  = redA[0][tid] + redA[1][tid] + redA[2][tid] + redA[3][tid];
    float sq = redB[0][tid] + redB[1][tid] + redB[2][tid] + redB[3][tid];
    float mean = s * (1.0f / 2048.0f);
    float var = (sq - 2048.0f * mean * mean) * (1.0f / 2047.0f);
    var = fmaxf(var, 0.0f);
    float istd = 1.0f / (sqrtf(var) + 1e-6f);
    a1v[tid] = istd * LOG2E;
    a0v[tid] = -mean * istd * LOG2E;
  }
  __syncthreads();

  float a0r[16], a1r[16], den[16];
#pragma unroll
  for (int r = 0; r < 16; ++r) {
    a0r[r] = a0v[qrow[r]];
    a1r[r] = a1v[qrow[r]];
    den[r] = 0.f;
  }

  f32x16 Oa[4] = {};

  for (int kt = 0; kt < 16; ++kt) {
    const float* Kb = Kp + (size_t)(b * SS + kt * 128 + w * 32) * DD;
    f32x16 acc = qk_tile(Kb, Qs, KVu[w], l31, lh8, lane);

    __syncthreads();
#pragma unroll
    for (int r = 0; r < 16; ++r) {
      float s = acc[r] * SCALE;
      float p = exp2f(fmaf(s, a1r[r], a0r[r]));
      den[r] += p;
      Psl[qrow[r] * PS_STRIDE + w * 32 + l31] = (bf16)p;
    }
    __syncthreads();

    const float* Vb = Vp + (size_t)(b * SS + kt * 128) * DD + w * 128 + 2 * lane;
    bf16* Vt = KVu[w];
    const int d0 = 2 * lane;
    for (int ks2 = 0; ks2 < 8; ++ks2) {
      const float* Vk = Vb + ks2 * 16 * DD;
#pragma unroll
      for (int i = 0; i < 8; ++i) {
        float2 va = *(const float2*)(Vk + (2 * i) * DD);
        float2 vc = *(const float2*)(Vk + (2 * i + 1) * DD);
        bf16x2 h0 = { (bf16)va.x, (bf16)vc.x };
        bf16x2 h1 = { (bf16)va.y, (bf16)vc.y };
        *(bf16x2*)&Vt[d0 * VT_STRIDE + 2 * i] = h0;
        *(bf16x2*)&Vt[(d0 + 1) * VT_STRIDE + 2 * i] = h1;
      }
      bf16x8 aP = *(const bf16x8*)&Psl[l31 * PS_STRIDE + ks2 * 16 + lh8];
#pragma unroll
      for (int dt = 0; dt < 4; ++dt) {
        const bf16* vr = &Vt[(dt * 32 + l31) * VT_STRIDE + lh8];
        bf16x2 e0 = *(const bf16x2*)(vr + 0);
        bf16x2 e1 = *(const bf16x2*)(vr + 2);
        bf16x2 e2 = *(const bf16x2*)(vr + 4);
        bf16x2 e3 = *(const bf16x2*)(vr + 6);
        bf16x8 bV = { e0.x, e0.y, e1.x, e1.y, e2.x, e2.y, e3.x, e3.y };
        Oa[dt] = __builtin_amdgcn_mfma_f32_32x32x16_bf16(aP, bV, Oa[dt], 0, 0, 0);
      }
    }
  }

#pragma unroll
  for (int r = 0; r < 16; ++r) {
    float v1 = den[r];
#pragma unroll
    for (int m = 16; m >= 1; m >>= 1) v1 += __shfl_xor(v1, m);
    if (l31 == 0) redA[w][qrow[r]] = v1;
  }
  __syncthreads();
  if (tid < 32) {
    float t = redA[0][tid] + redA[1][tid] + redA[2][tid] + redA[3][tid];
    idv[tid] = 1.0f / t;
  }
  __syncthreads();

  float idr[16];
#pragma unroll
  for (int r = 0; r < 16; ++r) idr[r] = idv[qrow[r]];

  float* Ob = Op + (size_t)(b * SS + q0) * DD + w * 128;
#pragma unroll
  for (int dt = 0; dt < 4; ++dt) {
#pragma unroll
    for (int r = 0; r < 16; ++r) {
      Ob[qrow[r] * DD + dt * 32 + l31] = Oa[dt][r] * idr[r];
    }
  }
}

// ---------------- launcher ----------------

extern "C" void kernel_launch(void* const* d_in, const int* in_sizes, int n_in,
                              void* d_out, int out_size, void* d_ws, size_t ws_size,
                              hipStream_t stream) {
  const float* Q = (const float*)d_in[0];
  const float* K = (const float*)d_in[1];
  const float* V = (const float*)d_in[2];
  float* out = (float*)d_out;
  (void)in_sizes; (void)n_in; (void)out_size;

  const size_t E = (size_t)BB * SS * DD;        // 4,194,304 elements per tensor
  const size_t SE = (size_t)BB * SS * SS;       // 16,777,216 score elements

  // ws layout (full path):
  //  [Kb bf16 E][Qb bf16 E][Vt bf16 E][S f16 SE][stats 2*B*S f][den B*S f][Opart 4*E f]
  const size_t off_S     = 3 * E * sizeof(bf16);           // 25,165,824
  const size_t off_stats = off_S + SE * sizeof(f16);       // 58,720,256
  const size_t off_den   = off_stats + 2 * BB * SS * 4;    // +65,536
  const size_t off_Opart = off_den + BB * SS * 4;          // +32,768
  const size_t need_full = off_Opart + 4 * E * sizeof(float); // 125,927,424
  const size_t need_mid  = 3 * E * sizeof(bf16);           // 25,165,824

  if (ws_size >= need_full) {
    char* ws = (char*)d_ws;
    bf16* Kb    = (bf16*)ws;
    bf16* Qb    = (bf16*)(ws + E * sizeof(bf16));
    bf16* Vt    = (bf16*)(ws + 2 * E * sizeof(bf16));
    f16*  Sp    = (f16*)(ws + off_S);
    float* stats = (float*)(ws + off_stats);
    float* den   = (float*)(ws + off_den);
    float* Opart = (float*)(ws + off_Opart);

    hipMemsetAsync(stats, 0, (2 * BB * SS + BB * SS) * sizeof(float), stream);
    cast_qk_kernel<<<(int)(E / 8 / 256), 256, 0, stream>>>(Q, K, Qb, Kb);
    transpose_v_kernel<<<dim3(SS / 64, DD / 64, BB), 256, 0, stream>>>(V, Vt);
    stats_kernel<<<dim3(SS / 32, 4, BB), 256, 0, stream>>>(Qb, Kb, Sp, stats);
    pv_kernel<<<dim3(SS / 32, 4, BB), 256, 0, stream>>>(Sp, stats, Vt, Opart, den);
    reduce_kernel<<<(int)(E / 4 / 256), 256, 0, stream>>>(Opart, den, out);
  } else if (ws_size >= need_mid) {
    bf16* Kb = (bf16*)d_ws;
    bf16* Qb = Kb + E;
    bf16* Vt = Qb + E;
    cast_qk_kernel<<<(int)(E / 8 / 256), 256, 0, stream>>>(Q, K, Qb, Kb);
    transpose_v_kernel<<<dim3(SS / 64, DD / 64, BB), 256, 0, stream>>>(V, Vt);
    nm_attn3_kernel<<<256, 512, 0, stream>>>(Qb, Kb, Vt, out);
  } else {
    nm_attn_kernel<<<dim3(SS / 32, BB), dim3(256, 1, 1), 0, stream>>>(Q, K, V, out);
  }
}